// Round 5
// baseline (305.142 us; speedup 1.0000x reference)
//
#include <hip/hip_runtime.h>
#include <hip/hip_bf16.h>
#include <math.h>

#define H 128
#define EPS 1e-5f
#define INF_BIAS 0.1f

typedef __attribute__((ext_vector_type(8))) short bf16x8;
typedef __attribute__((ext_vector_type(4))) float f32x4;

// ---- bf16 helpers (RNE) ----
__device__ inline unsigned short f2bf_rne(float f) {
    unsigned u = __float_as_uint(f);
    u += 0x7fffu + ((u >> 16) & 1u);
    return (unsigned short)(u >> 16);
}
__device__ inline float bf2f(unsigned short h) {
    return __uint_as_float(((unsigned)h) << 16);
}
__device__ inline unsigned pack2(float a, float b) {
    return (unsigned)f2bf_rne(a) | ((unsigned)f2bf_rne(b) << 16);
}
__device__ inline float2 unpack2(unsigned v) {
    float2 r;
    r.x = __uint_as_float(v << 16);
    r.y = __uint_as_float(v & 0xffff0000u);
    return r;
}

// ---------------------------------------------------------------------------
// prep: BN-prescaled bf16 W, written in MFMA A-fragment order ("swizzled"):
//   fragment f = nt*4+kt  (nt: 16-col group, kt: 32-k group)
//   lane t = q*16+c holds W[j = nt*16+c][k = kt*32+q*8 .. +8)
//   chunk address = f*1024B + t*16B   -> proj reads LDS at base + lane*16B
// Also d_user[j] = a_j*(b1_j - rm_j) + beta_j.
// grid: 32 blocks (f) x 64 threads (t)
// ---------------------------------------------------------------------------
__global__ void prep_kernel(
    const float* __restrict__ W1, const float* __restrict__ b1,
    const float* __restrict__ gamma, const float* __restrict__ beta,
    const float* __restrict__ rm, const float* __restrict__ rv,
    unsigned short* __restrict__ Wswz_u, unsigned short* __restrict__ Wswz_f,
    float* __restrict__ d_user)
{
    const int f  = blockIdx.x;        // 0..31
    const int nt = f >> 2, kt = f & 3;
    const int t  = threadIdx.x;       // 0..63
    const int c  = t & 15, q = t >> 4;

    const int j  = nt * 16 + c;
    const float a = gamma[j] * rsqrtf(rv[j] + EPS);
    const int k0 = kt * 32 + q * 8;

    unsigned short wu[8], wf[8];
    #pragma unroll
    for (int i = 0; i < 8; ++i) {
        wu[i] = f2bf_rne(a * W1[(size_t)j * (2 * H) + k0 + i]);
        wf[i] = f2bf_rne(a * W1[(size_t)j * (2 * H) + H + k0 + i]);
    }
    const size_t dst = (size_t)f * 1024 / 2 + (size_t)t * 8;   // in ushort units
    #pragma unroll
    for (int i = 0; i < 8; ++i) { Wswz_u[dst + i] = wu[i]; Wswz_f[dst + i] = wf[i]; }

    if (kt == 0 && q == 0) d_user[j] = a * (b1[j] - rm[j]) + beta[j];
}

// ---------------------------------------------------------------------------
// proj_mfma v3: W fragments in LDS (fragment-ordered, conflict-free b128
// reads), low VGPR -> 4 waves/SIMD for latency hiding. Z split hi+lo bf16
// (2 MFMAs) = same arithmetic as round 4. Each wave owns a 16-row x 128-col
// strip per iteration, grid-strides over row tiles.
// ---------------------------------------------------------------------------
__global__ __launch_bounds__(256, 4) void proj_mfma(
    const float* __restrict__ z_user, const float* __restrict__ z_food,
    const unsigned short* __restrict__ Wswz_u, const unsigned short* __restrict__ Wswz_f,
    const float* __restrict__ d_user,
    unsigned short* __restrict__ U, unsigned short* __restrict__ F,
    int n_users, int n_foods, int GU, int GB)
{
    __shared__ unsigned short Wlds[32 * 64 * 8];   // 32 KB, fragment order

    const bool userMode = (blockIdx.x < (unsigned)GU);
    const float* Z;
    const unsigned short* Wsrc;
    unsigned short* Out;
    int n, blk0, nblk;
    if (userMode) { Z = z_user; Wsrc = Wswz_u; Out = U; n = n_users; blk0 = blockIdx.x;      nblk = GU; }
    else          { Z = z_food; Wsrc = Wswz_f; Out = F; n = n_foods; blk0 = blockIdx.x - GU; nblk = GB - GU; }
    const int tiles = (n + 15) >> 4;

    // ---- stage swizzled W into LDS (32 KB, coalesced)
    {
        const uint4* src = (const uint4*)Wsrc;
        uint4* dst = (uint4*)Wlds;
        #pragma unroll
        for (int i = 0; i < 8; ++i)
            dst[i * 256 + threadIdx.x] = src[i * 256 + threadIdx.x];
    }
    __syncthreads();

    const int wave = threadIdx.x >> 6;
    const int lane = threadIdx.x & 63;
    const int c = lane & 15;   // D col -> row r within tile; Z row for B
    const int q = lane >> 4;   // quad  -> k-group for A/B; j-subgroup for D

    // ---- BN offset folded into accumulator init
    f32x4 dvec[8];
    #pragma unroll
    for (int nt = 0; nt < 8; ++nt) {
        if (userMode) {
            float4 d = *(const float4*)(d_user + nt * 16 + q * 4);
            dvec[nt] = (f32x4){d.x, d.y, d.z, d.w};
        } else {
            dvec[nt] = (f32x4){0.f, 0.f, 0.f, 0.f};
        }
    }

    const int wid = blk0 * 4 + wave;
    const int nw  = nblk * 4;

    for (int t = wid; t < tiles; t += nw) {
        const int r = t * 16 + c;
        const float* zrow = Z + (size_t)min(r, n - 1) * H;

        // ---- load this lane's Z segments (8 x 16B, hoistable) and split
        bf16x8 zhi[4], zlo[4];
        #pragma unroll
        for (int kt = 0; kt < 4; ++kt) {
            const int k0 = kt * 32 + q * 8;
            float4 za = ((const float4*)(zrow + k0))[0];
            float4 zb = ((const float4*)(zrow + k0))[1];
            float v[8] = {za.x, za.y, za.z, za.w, zb.x, zb.y, zb.z, zb.w};
            #pragma unroll
            for (int i = 0; i < 8; ++i) {
                unsigned short hi = f2bf_rne(v[i]);
                unsigned short lo = f2bf_rne(v[i] - bf2f(hi));
                zhi[kt][i] = (short)hi; zlo[kt][i] = (short)lo;
            }
        }

        f32x4 acc[8];
        #pragma unroll
        for (int nt = 0; nt < 8; ++nt) acc[nt] = dvec[nt];

        #pragma unroll
        for (int kt = 0; kt < 4; ++kt) {
            #pragma unroll
            for (int nt = 0; nt < 8; ++nt) {
                bf16x8 wv = *(const bf16x8*)&Wlds[((nt * 4 + kt) * 64 + lane) * 8];
                acc[nt] = __builtin_amdgcn_mfma_f32_16x16x32_bf16(wv, zhi[kt], acc[nt], 0, 0, 0);
                acc[nt] = __builtin_amdgcn_mfma_f32_16x16x32_bf16(wv, zlo[kt], acc[nt], 0, 0, 0);
            }
        }

        // ---- packed epilogue: lane (c,q) holds row r, cols nt*16+q*4+{0..3}
        if (r < n) {
            unsigned short* orow = Out + (size_t)r * H + q * 4;
            #pragma unroll
            for (int nt = 0; nt < 8; ++nt) {
                uint2 p;
                p.x = pack2(acc[nt][0], acc[nt][1]);
                p.y = pack2(acc[nt][2], acc[nt][3]);
                *(uint2*)(orow + nt * 16) = p;
            }
        }
    }
}

// ---------------------------------------------------------------------------
// edge kernel: per-edge gather + relu-dot + sigmoid, bf16 tables (unchanged).
// ---------------------------------------------------------------------------
__global__ __launch_bounds__(256) void edge_kernel(
    const unsigned short* __restrict__ U, const unsigned short* __restrict__ F,
    const int* __restrict__ row, const int* __restrict__ col,
    const float* __restrict__ W2, const float* __restrict__ b2,
    float* __restrict__ out, int E)
{
    const int lane = threadIdx.x & 15;
    const int g       = (blockIdx.x * blockDim.x + threadIdx.x) >> 4;
    const int nGroups = (gridDim.x * blockDim.x) >> 4;

    const float4 w2a = ((const float4*)W2)[2 * lane];
    const float4 w2b = ((const float4*)W2)[2 * lane + 1];
    const float bias = b2[0] + INF_BIAS;

    for (int e = g; e < E; e += nGroups) {
        int u = row[e];
        int f = col[e];
        uint4 uv = ((const uint4*)(U + (size_t)u * H))[lane];
        uint4 fv = ((const uint4*)(F + (size_t)f * H))[lane];

        float2 u0 = unpack2(uv.x), f0 = unpack2(fv.x);
        float2 u1 = unpack2(uv.y), f1 = unpack2(fv.y);
        float2 u2 = unpack2(uv.z), f2 = unpack2(fv.z);
        float2 u3 = unpack2(uv.w), f3 = unpack2(fv.w);

        float s =
            w2a.x * fmaxf(u0.x + f0.x, 0.0f) +
            w2a.y * fmaxf(u0.y + f0.y, 0.0f) +
            w2a.z * fmaxf(u1.x + f1.x, 0.0f) +
            w2a.w * fmaxf(u1.y + f1.y, 0.0f) +
            w2b.x * fmaxf(u2.x + f2.x, 0.0f) +
            w2b.y * fmaxf(u2.y + f2.y, 0.0f) +
            w2b.z * fmaxf(u3.x + f3.x, 0.0f) +
            w2b.w * fmaxf(u3.y + f3.y, 0.0f);

        s += __shfl_xor(s, 8, 16);
        s += __shfl_xor(s, 4, 16);
        s += __shfl_xor(s, 2, 16);
        s += __shfl_xor(s, 1, 16);

        if (lane == 0) {
            float x = s + bias;
            out[e] = 1.0f / (1.0f + __expf(-x));
        }
    }
}

extern "C" void kernel_launch(void* const* d_in, const int* in_sizes, int n_in,
                              void* d_out, int out_size, void* d_ws, size_t ws_size,
                              hipStream_t stream) {
    const float* z_user = (const float*)d_in[0];
    const float* z_food = (const float*)d_in[1];
    const int*   row    = (const int*)d_in[2];
    const int*   col    = (const int*)d_in[3];
    const float* W1     = (const float*)d_in[4];
    const float* b1     = (const float*)d_in[5];
    const float* gamma  = (const float*)d_in[6];
    const float* beta   = (const float*)d_in[7];
    const float* rm     = (const float*)d_in[8];
    const float* rv     = (const float*)d_in[9];
    const float* W2     = (const float*)d_in[10];
    const float* b2     = (const float*)d_in[11];
    float* out = (float*)d_out;

    const int n_users = in_sizes[0] / H;
    const int n_foods = in_sizes[1] / H;
    const int E       = in_sizes[2];

    // workspace layout
    unsigned short* U      = (unsigned short*)d_ws;        // n_users*128 bf16
    unsigned short* F      = U + (size_t)n_users * H;      // n_foods*128 bf16
    unsigned short* Wswz_u = F + (size_t)n_foods * H;      // 128*128 bf16, frag order
    unsigned short* Wswz_f = Wswz_u + H * H;               // 128*128 bf16, frag order
    float*          d_usr  = (float*)(Wswz_f + H * H);     // 128 f32

    prep_kernel<<<32, 64, 0, stream>>>(W1, b1, gamma, beta, rm, rv,
                                       Wswz_u, Wswz_f, d_usr);

    // ~4 blocks/CU; 2:1 user:food split matches the row ratio
    const int GU = 683, GB = 1024;
    proj_mfma<<<GB, 256, 0, stream>>>(z_user, z_food, Wswz_u, Wswz_f, d_usr,
                                      U, F, n_users, n_foods, GU, GB);

    edge_kernel<<<8192, 256, 0, stream>>>(U, F, row, col, W2, b2, out, E);
}

// Round 6
// 234.202 us; speedup vs baseline: 1.3029x; 1.3029x over previous
//
#include <hip/hip_runtime.h>
#include <hip/hip_bf16.h>
#include <math.h>

#define H 128
#define EPS 1e-5f
#define INF_BIAS 0.1f

typedef __attribute__((ext_vector_type(8))) short bf16x8;
typedef __attribute__((ext_vector_type(4))) float f32x4;

// ---- bf16 helpers (RNE) ----
__device__ inline unsigned short f2bf_rne(float f) {
    unsigned u = __float_as_uint(f);
    u += 0x7fffu + ((u >> 16) & 1u);
    return (unsigned short)(u >> 16);
}
__device__ inline float bf2f(unsigned short h) {
    return __uint_as_float(((unsigned)h) << 16);
}
__device__ inline unsigned pack2(float a, float b) {
    return (unsigned)f2bf_rne(a) | ((unsigned)f2bf_rne(b) << 16);
}
__device__ inline float2 unpack2(unsigned v) {
    float2 r;
    r.x = __uint_as_float(v << 16);
    r.y = __uint_as_float(v & 0xffff0000u);
    return r;
}

// ---------------------------------------------------------------------------
// prep: BN-prescaled bf16(hi) W tables (row-major) + user offset vector.
//   Whi_u[j][k] = bf16(a_j * W1[j][k]);  Whi_f[j][k] = bf16(a_j * W1[j][128+k])
//   d_user[j]   = a_j*(b1_j - rm_j) + beta_j,  a_j = gamma_j*rsqrt(rv_j+eps)
// ---------------------------------------------------------------------------
__global__ void prep_kernel(
    const float* __restrict__ W1, const float* __restrict__ b1,
    const float* __restrict__ gamma, const float* __restrict__ beta,
    const float* __restrict__ rm, const float* __restrict__ rv,
    unsigned short* __restrict__ Whi_u, unsigned short* __restrict__ Whi_f,
    float* __restrict__ d_user)
{
    int j = blockIdx.x;
    int k = threadIdx.x;
    float a = gamma[j] * rsqrtf(rv[j] + EPS);
    Whi_u[j * H + k] = f2bf_rne(a * W1[(size_t)j * (2 * H) + k]);
    Whi_f[j * H + k] = f2bf_rne(a * W1[(size_t)j * (2 * H) + H + k]);
    if (k == 0) d_user[j] = a * (b1[j] - rm[j]) + beta[j];
}

// ---------------------------------------------------------------------------
// proj_mfma v4: W register-stationary, col-split across wave pairs.
// Each wave holds W-frags for 64 output cols (16 frags = 64 VGPR) -> ~110
// VGPR total -> 4 waves/SIMD. Block owns a CONTIGUOUS tile chunk (round-3's
// proven-ideal write/fetch locality): waves {0,1} = col halves of even tiles,
// {2,3} = odd tiles. A=W (m=col j), B=Z (n=row r): lane's 4 acc regs are 4
// consecutive cols of one row -> packed 8B stores. Z split hi+lo (2 MFMAs).
// ---------------------------------------------------------------------------
__global__ __launch_bounds__(256) void proj_mfma(
    const float* __restrict__ z_user, const float* __restrict__ z_food,
    const unsigned short* __restrict__ Whi_u, const unsigned short* __restrict__ Whi_f,
    const float* __restrict__ d_user,
    unsigned short* __restrict__ U, unsigned short* __restrict__ F,
    int n_users, int n_foods, int GU, int GB)
{
    const bool userMode = (blockIdx.x < (unsigned)GU);
    const float* Z;
    const unsigned short* Wt;
    unsigned short* Out;
    int n, blk0, nblk;
    if (userMode) { Z = z_user; Wt = Whi_u; Out = U; n = n_users; blk0 = blockIdx.x;      nblk = GU; }
    else          { Z = z_food; Wt = Whi_f; Out = F; n = n_foods; blk0 = blockIdx.x - GU; nblk = GB - GU; }
    const int tiles = (n + 15) >> 4;
    const int tpb   = (tiles + nblk - 1) / nblk;          // tiles per block
    const int t0    = blk0 * tpb;
    const int t1    = min(t0 + tpb, tiles);

    const int wave = threadIdx.x >> 6;
    const int lane = threadIdx.x & 63;
    const int c = lane & 15;       // Z row within tile (B n-index / D col-index)
    const int q = lane >> 4;       // k-group for A/B; col-subgroup for D
    const int half = wave & 1;     // which 64-col half this wave computes
    const int wsub = wave >> 1;    // tile parity

    // ---- preload this wave's 16 W fragments (64 VGPR), L2-hot source
    bf16x8 wf[4][4];
    #pragma unroll
    for (int nt = 0; nt < 4; ++nt)
        #pragma unroll
        for (int kt = 0; kt < 4; ++kt)
            wf[nt][kt] = *(const bf16x8*)(Wt + (size_t)(half * 64 + nt * 16 + c) * H + kt * 32 + q * 8);

    // ---- BN offset folded into accumulator init
    f32x4 dvec[4];
    #pragma unroll
    for (int nt = 0; nt < 4; ++nt) {
        if (userMode) {
            float4 d = *(const float4*)(d_user + half * 64 + nt * 16 + q * 4);
            dvec[nt] = (f32x4){d.x, d.y, d.z, d.w};
        } else {
            dvec[nt] = (f32x4){0.f, 0.f, 0.f, 0.f};
        }
    }

    for (int t = t0 + wsub; t < t1; t += 2) {
        const int r = t * 16 + c;
        const float* zrow = Z + (size_t)min(r, n - 1) * H;

        f32x4 acc[4];
        #pragma unroll
        for (int nt = 0; nt < 4; ++nt) acc[nt] = dvec[nt];

        #pragma unroll
        for (int kt = 0; kt < 4; ++kt) {
            const int k0 = kt * 32 + q * 8;
            float4 za = ((const float4*)(zrow + k0))[0];
            float4 zb = ((const float4*)(zrow + k0))[1];
            bf16x8 zhi, zlo;
            {
                float v[8] = {za.x, za.y, za.z, za.w, zb.x, zb.y, zb.z, zb.w};
                #pragma unroll
                for (int i = 0; i < 8; ++i) {
                    unsigned short hi = f2bf_rne(v[i]);
                    unsigned short lo = f2bf_rne(v[i] - bf2f(hi));
                    zhi[i] = (short)hi; zlo[i] = (short)lo;
                }
            }
            #pragma unroll
            for (int nt = 0; nt < 4; ++nt) {
                acc[nt] = __builtin_amdgcn_mfma_f32_16x16x32_bf16(wf[nt][kt], zhi, acc[nt], 0, 0, 0);
                acc[nt] = __builtin_amdgcn_mfma_f32_16x16x32_bf16(wf[nt][kt], zlo, acc[nt], 0, 0, 0);
            }
        }

        // ---- packed epilogue: lane (c,q) -> row r, cols half*64+nt*16+q*4+{0..3}
        if (r < n) {
            unsigned short* orow = Out + (size_t)r * H + half * 64 + q * 4;
            #pragma unroll
            for (int nt = 0; nt < 4; ++nt) {
                uint2 p;
                p.x = pack2(acc[nt][0], acc[nt][1]);
                p.y = pack2(acc[nt][2], acc[nt][3]);
                *(uint2*)(orow + nt * 16) = p;
            }
        }
    }
}

// ---------------------------------------------------------------------------
// edge kernel: per-edge gather + relu-dot + sigmoid, bf16 tables (unchanged).
// ---------------------------------------------------------------------------
__global__ __launch_bounds__(256) void edge_kernel(
    const unsigned short* __restrict__ U, const unsigned short* __restrict__ F,
    const int* __restrict__ row, const int* __restrict__ col,
    const float* __restrict__ W2, const float* __restrict__ b2,
    float* __restrict__ out, int E)
{
    const int lane = threadIdx.x & 15;
    const int g       = (blockIdx.x * blockDim.x + threadIdx.x) >> 4;
    const int nGroups = (gridDim.x * blockDim.x) >> 4;

    const float4 w2a = ((const float4*)W2)[2 * lane];
    const float4 w2b = ((const float4*)W2)[2 * lane + 1];
    const float bias = b2[0] + INF_BIAS;

    for (int e = g; e < E; e += nGroups) {
        int u = row[e];
        int f = col[e];
        uint4 uv = ((const uint4*)(U + (size_t)u * H))[lane];
        uint4 fv = ((const uint4*)(F + (size_t)f * H))[lane];

        float2 u0 = unpack2(uv.x), f0 = unpack2(fv.x);
        float2 u1 = unpack2(uv.y), f1 = unpack2(fv.y);
        float2 u2 = unpack2(uv.z), f2 = unpack2(fv.z);
        float2 u3 = unpack2(uv.w), f3 = unpack2(fv.w);

        float s =
            w2a.x * fmaxf(u0.x + f0.x, 0.0f) +
            w2a.y * fmaxf(u0.y + f0.y, 0.0f) +
            w2a.z * fmaxf(u1.x + f1.x, 0.0f) +
            w2a.w * fmaxf(u1.y + f1.y, 0.0f) +
            w2b.x * fmaxf(u2.x + f2.x, 0.0f) +
            w2b.y * fmaxf(u2.y + f2.y, 0.0f) +
            w2b.z * fmaxf(u3.x + f3.x, 0.0f) +
            w2b.w * fmaxf(u3.y + f3.y, 0.0f);

        s += __shfl_xor(s, 8, 16);
        s += __shfl_xor(s, 4, 16);
        s += __shfl_xor(s, 2, 16);
        s += __shfl_xor(s, 1, 16);

        if (lane == 0) {
            float x = s + bias;
            out[e] = 1.0f / (1.0f + __expf(-x));
        }
    }
}

extern "C" void kernel_launch(void* const* d_in, const int* in_sizes, int n_in,
                              void* d_out, int out_size, void* d_ws, size_t ws_size,
                              hipStream_t stream) {
    const float* z_user = (const float*)d_in[0];
    const float* z_food = (const float*)d_in[1];
    const int*   row    = (const int*)d_in[2];
    const int*   col    = (const int*)d_in[3];
    const float* W1     = (const float*)d_in[4];
    const float* b1     = (const float*)d_in[5];
    const float* gamma  = (const float*)d_in[6];
    const float* beta   = (const float*)d_in[7];
    const float* rm     = (const float*)d_in[8];
    const float* rv     = (const float*)d_in[9];
    const float* W2     = (const float*)d_in[10];
    const float* b2     = (const float*)d_in[11];
    float* out = (float*)d_out;

    const int n_users = in_sizes[0] / H;
    const int n_foods = in_sizes[1] / H;
    const int E       = in_sizes[2];

    // workspace layout
    unsigned short* U     = (unsigned short*)d_ws;        // n_users*128 bf16
    unsigned short* F     = U + (size_t)n_users * H;      // n_foods*128 bf16
    unsigned short* Whi_u = F + (size_t)n_foods * H;      // 128*128 bf16
    unsigned short* Whi_f = Whi_u + H * H;                // 128*128 bf16
    float*          d_usr = (float*)(Whi_f + H * H);      // 128 f32

    prep_kernel<<<H, H, 0, stream>>>(W1, b1, gamma, beta, rm, rv,
                                     Whi_u, Whi_f, d_usr);

    // contiguous tile chunks per block; 2:1 user:food split; ~4 blocks/CU
    const int GU = 682, GB = 1024;
    proj_mfma<<<GB, 256, 0, stream>>>(z_user, z_food, Whi_u, Whi_f, d_usr,
                                      U, F, n_users, n_foods, GU, GB);

    edge_kernel<<<8192, 256, 0, stream>>>(U, F, row, col, W2, b2, out, E);
}

// Round 7
// 221.523 us; speedup vs baseline: 1.3775x; 1.0572x over previous
//
#include <hip/hip_runtime.h>
#include <hip/hip_bf16.h>
#include <math.h>

#define H 128
#define EPS 1e-5f
#define INF_BIAS 0.1f

typedef __attribute__((ext_vector_type(8))) short bf16x8;
typedef __attribute__((ext_vector_type(4))) float f32x4;

// ---- bf16 helpers (RNE) ----
__device__ inline unsigned short f2bf_rne(float f) {
    unsigned u = __float_as_uint(f);
    u += 0x7fffu + ((u >> 16) & 1u);
    return (unsigned short)(u >> 16);
}
__device__ inline float bf2f(unsigned short h) {
    return __uint_as_float(((unsigned)h) << 16);
}
__device__ inline unsigned pack2(float a, float b) {
    return (unsigned)f2bf_rne(a) | ((unsigned)f2bf_rne(b) << 16);
}
__device__ inline float2 unpack2(unsigned v) {
    float2 r;
    r.x = __uint_as_float(v << 16);
    r.y = __uint_as_float(v & 0xffff0000u);
    return r;
}

// ---------------------------------------------------------------------------
// prep: BN-prescaled bf16 W in MFMA A-fragment order with a PERMUTED j->m
// mapping chosen so the proj epilogue is contiguous:
//   frag f = half*16 + nt*4 + kt   (half: 64-col half, nt: 4-col group, kt: 32-k)
//   lane t = q*16 + c (c = A's m index) holds
//       j = half*64 + (c>>2)*16 + nt*4 + (c&3),   k = kt*32 + q*8 .. +8
// => in D, lane (c,q) accumulates cols half*64 + q*16 + nt*4 + reg of row c,
//    i.e. 16 consecutive cols across nt -> two 16B packed stores per lane.
// Also d_user[j] = a_j*(b1_j - rm_j) + beta_j.
// grid: 32 blocks (f) x 64 threads (t)
// ---------------------------------------------------------------------------
__global__ void prep_kernel(
    const float* __restrict__ W1, const float* __restrict__ b1,
    const float* __restrict__ gamma, const float* __restrict__ beta,
    const float* __restrict__ rm, const float* __restrict__ rv,
    unsigned short* __restrict__ Wswz_u, unsigned short* __restrict__ Wswz_f,
    float* __restrict__ d_user)
{
    const int f    = blockIdx.x;          // 0..31
    const int half = f >> 4, nt = (f >> 2) & 3, kt = f & 3;
    const int t    = threadIdx.x;         // 0..63
    const int c    = t & 15, q = t >> 4;

    const int j  = half * 64 + (c >> 2) * 16 + nt * 4 + (c & 3);
    const float a = gamma[j] * rsqrtf(rv[j] + EPS);
    const int k0 = kt * 32 + q * 8;

    unsigned short wu[8], wf[8];
    #pragma unroll
    for (int i = 0; i < 8; ++i) {
        wu[i] = f2bf_rne(a * W1[(size_t)j * (2 * H) + k0 + i]);
        wf[i] = f2bf_rne(a * W1[(size_t)j * (2 * H) + H + k0 + i]);
    }
    const size_t dst = (size_t)f * 512 + (size_t)t * 8;   // ushort units
    #pragma unroll
    for (int i = 0; i < 8; ++i) { Wswz_u[dst + i] = wu[i]; Wswz_f[dst + i] = wf[i]; }

    if (kt == 0 && q == 0) d_user[j] = a * (b1[j] - rm[j]) + beta[j];
}

// ---------------------------------------------------------------------------
// proj_mfma v5: W register-stationary (16 frags = 64 VGPR per wave, col-half
// split), one contiguous 32-row chunk per block (2 tiles; waves {0,1}=tile0
// halves, {2,3}=tile1 halves), permuted-j fragments -> contiguous 2x16B
// epilogue stores (full-line writes, no LDS). Z split hi+lo bf16 (2 MFMAs),
// arithmetic identical to rounds 4-6.
// ---------------------------------------------------------------------------
__global__ __launch_bounds__(256, 4) void proj_mfma(
    const float* __restrict__ z_user, const float* __restrict__ z_food,
    const unsigned short* __restrict__ Wswz_u, const unsigned short* __restrict__ Wswz_f,
    const float* __restrict__ d_user,
    unsigned short* __restrict__ U, unsigned short* __restrict__ F,
    int n_users, int n_foods, int GU)
{
    const bool userMode = (blockIdx.x < (unsigned)GU);
    const float* Z;
    const unsigned short* Wsrc;
    unsigned short* Out;
    int n, blk0;
    if (userMode) { Z = z_user; Wsrc = Wswz_u; Out = U; n = n_users; blk0 = blockIdx.x; }
    else          { Z = z_food; Wsrc = Wswz_f; Out = F; n = n_foods; blk0 = blockIdx.x - GU; }
    const int tiles = n >> 4;   // n is a multiple of 16 (100000, 50000)

    const int wave = threadIdx.x >> 6;
    const int lane = threadIdx.x & 63;
    const int c = lane & 15;        // B n-index -> row within tile; D col-index
    const int q = lane >> 4;        // k-group for A/B; 16-col subgroup for D
    const int half    = wave & 1;   // 64-col half
    const int tilepar = wave >> 1;  // which of the block's 2 tiles

    const int t = blk0 * 2 + tilepar;
    if (t >= tiles) return;         // only the last (odd) food block hits this

    // ---- preload this wave's 16 W fragments (64 VGPR) from the L2-hot table
    bf16x8 wf[4][4];
    #pragma unroll
    for (int nt = 0; nt < 4; ++nt)
        #pragma unroll
        for (int kt = 0; kt < 4; ++kt)
            wf[nt][kt] = *(const bf16x8*)(Wsrc + (size_t)(half * 16 + nt * 4 + kt) * 512 + lane * 8);

    // ---- BN offset folded into accumulator init (cols half*64+q*16+nt*4+{0..3})
    f32x4 acc[4];
    #pragma unroll
    for (int nt = 0; nt < 4; ++nt) {
        if (userMode) {
            float4 d = *(const float4*)(d_user + half * 64 + q * 16 + nt * 4);
            acc[nt] = (f32x4){d.x, d.y, d.z, d.w};
        } else {
            acc[nt] = (f32x4){0.f, 0.f, 0.f, 0.f};
        }
    }

    const int r = t * 16 + c;
    const float* zrow = Z + (size_t)r * H;

    #pragma unroll
    for (int kt = 0; kt < 4; ++kt) {
        const int k0 = kt * 32 + q * 8;
        float4 za = ((const float4*)(zrow + k0))[0];
        float4 zb = ((const float4*)(zrow + k0))[1];
        bf16x8 zhi, zlo;
        {
            float v[8] = {za.x, za.y, za.z, za.w, zb.x, zb.y, zb.z, zb.w};
            #pragma unroll
            for (int i = 0; i < 8; ++i) {
                unsigned short hi = f2bf_rne(v[i]);
                unsigned short lo = f2bf_rne(v[i] - bf2f(hi));
                zhi[i] = (short)hi; zlo[i] = (short)lo;
            }
        }
        #pragma unroll
        for (int nt = 0; nt < 4; ++nt) {
            acc[nt] = __builtin_amdgcn_mfma_f32_16x16x32_bf16(wf[nt][kt], zhi, acc[nt], 0, 0, 0);
            acc[nt] = __builtin_amdgcn_mfma_f32_16x16x32_bf16(wf[nt][kt], zlo, acc[nt], 0, 0, 0);
        }
    }

    // ---- contiguous epilogue: lane (c,q) owns cols half*64+q*16 .. +16 of row r
    unsigned short* obase = Out + (size_t)r * H + half * 64 + q * 16;
    uint4 p0, p1;
    p0.x = pack2(acc[0][0], acc[0][1]); p0.y = pack2(acc[0][2], acc[0][3]);
    p0.z = pack2(acc[1][0], acc[1][1]); p0.w = pack2(acc[1][2], acc[1][3]);
    p1.x = pack2(acc[2][0], acc[2][1]); p1.y = pack2(acc[2][2], acc[2][3]);
    p1.z = pack2(acc[3][0], acc[3][1]); p1.w = pack2(acc[3][2], acc[3][3]);
    *(uint4*)(obase)     = p0;
    *(uint4*)(obase + 8) = p1;
}

// ---------------------------------------------------------------------------
// edge kernel: per-edge gather + relu-dot + sigmoid, bf16 tables (unchanged).
// ---------------------------------------------------------------------------
__global__ __launch_bounds__(256) void edge_kernel(
    const unsigned short* __restrict__ U, const unsigned short* __restrict__ F,
    const int* __restrict__ row, const int* __restrict__ col,
    const float* __restrict__ W2, const float* __restrict__ b2,
    float* __restrict__ out, int E)
{
    const int lane = threadIdx.x & 15;
    const int g       = (blockIdx.x * blockDim.x + threadIdx.x) >> 4;
    const int nGroups = (gridDim.x * blockDim.x) >> 4;

    const float4 w2a = ((const float4*)W2)[2 * lane];
    const float4 w2b = ((const float4*)W2)[2 * lane + 1];
    const float bias = b2[0] + INF_BIAS;

    for (int e = g; e < E; e += nGroups) {
        int u = row[e];
        int f = col[e];
        uint4 uv = ((const uint4*)(U + (size_t)u * H))[lane];
        uint4 fv = ((const uint4*)(F + (size_t)f * H))[lane];

        float2 u0 = unpack2(uv.x), f0 = unpack2(fv.x);
        float2 u1 = unpack2(uv.y), f1 = unpack2(fv.y);
        float2 u2 = unpack2(uv.z), f2 = unpack2(fv.z);
        float2 u3 = unpack2(uv.w), f3 = unpack2(fv.w);

        float s =
            w2a.x * fmaxf(u0.x + f0.x, 0.0f) +
            w2a.y * fmaxf(u0.y + f0.y, 0.0f) +
            w2a.z * fmaxf(u1.x + f1.x, 0.0f) +
            w2a.w * fmaxf(u1.y + f1.y, 0.0f) +
            w2b.x * fmaxf(u2.x + f2.x, 0.0f) +
            w2b.y * fmaxf(u2.y + f2.y, 0.0f) +
            w2b.z * fmaxf(u3.x + f3.x, 0.0f) +
            w2b.w * fmaxf(u3.y + f3.y, 0.0f);

        s += __shfl_xor(s, 8, 16);
        s += __shfl_xor(s, 4, 16);
        s += __shfl_xor(s, 2, 16);
        s += __shfl_xor(s, 1, 16);

        if (lane == 0) {
            float x = s + bias;
            out[e] = 1.0f / (1.0f + __expf(-x));
        }
    }
}

extern "C" void kernel_launch(void* const* d_in, const int* in_sizes, int n_in,
                              void* d_out, int out_size, void* d_ws, size_t ws_size,
                              hipStream_t stream) {
    const float* z_user = (const float*)d_in[0];
    const float* z_food = (const float*)d_in[1];
    const int*   row    = (const int*)d_in[2];
    const int*   col    = (const int*)d_in[3];
    const float* W1     = (const float*)d_in[4];
    const float* b1     = (const float*)d_in[5];
    const float* gamma  = (const float*)d_in[6];
    const float* beta   = (const float*)d_in[7];
    const float* rm     = (const float*)d_in[8];
    const float* rv     = (const float*)d_in[9];
    const float* W2     = (const float*)d_in[10];
    const float* b2     = (const float*)d_in[11];
    float* out = (float*)d_out;

    const int n_users = in_sizes[0] / H;
    const int n_foods = in_sizes[1] / H;
    const int E       = in_sizes[2];

    // workspace layout
    unsigned short* U      = (unsigned short*)d_ws;        // n_users*128 bf16
    unsigned short* F      = U + (size_t)n_users * H;      // n_foods*128 bf16
    unsigned short* Wswz_u = F + (size_t)n_foods * H;      // 128*128 bf16, frag order
    unsigned short* Wswz_f = Wswz_u + H * H;               // 128*128 bf16, frag order
    float*          d_usr  = (float*)(Wswz_f + H * H);     // 128 f32

    prep_kernel<<<32, 64, 0, stream>>>(W1, b1, gamma, beta, rm, rv,
                                       Wswz_u, Wswz_f, d_usr);

    // one 32-row chunk per block: users 100000/32 = 3125, foods ceil(3125/2)=1563
    const int GU = (n_users + 31) / 32;
    const int GF = ((n_foods + 15) / 16 + 1) / 2;
    proj_mfma<<<GU + GF, 256, 0, stream>>>(z_user, z_food, Wswz_u, Wswz_f, d_usr,
                                           U, F, n_users, n_foods, GU);

    edge_kernel<<<8192, 256, 0, stream>>>(U, F, row, col, W2, b2, out, E);
}

// Round 8
// 220.980 us; speedup vs baseline: 1.3809x; 1.0025x over previous
//
#include <hip/hip_runtime.h>
#include <hip/hip_bf16.h>
#include <math.h>

#define H 128
#define EPS 1e-5f
#define INF_BIAS 0.1f

typedef __attribute__((ext_vector_type(8))) short bf16x8;
typedef __attribute__((ext_vector_type(4))) float f32x4;

// ---- bf16 helpers (RNE) ----
__device__ inline unsigned short f2bf_rne(float f) {
    unsigned u = __float_as_uint(f);
    u += 0x7fffu + ((u >> 16) & 1u);
    return (unsigned short)(u >> 16);
}
__device__ inline float bf2f(unsigned short h) {
    return __uint_as_float(((unsigned)h) << 16);
}
__device__ inline unsigned pack2(float a, float b) {
    return (unsigned)f2bf_rne(a) | ((unsigned)f2bf_rne(b) << 16);
}
__device__ inline float2 unpack2(unsigned v) {
    float2 r;
    r.x = __uint_as_float(v << 16);
    r.y = __uint_as_float(v & 0xffff0000u);
    return r;
}

// ---------------------------------------------------------------------------
// prep: BN-prescaled bf16 W in MFMA A-fragment order with a PERMUTED j->m
// mapping chosen so the proj epilogue is contiguous (see round 7 notes).
// ---------------------------------------------------------------------------
__global__ void prep_kernel(
    const float* __restrict__ W1, const float* __restrict__ b1,
    const float* __restrict__ gamma, const float* __restrict__ beta,
    const float* __restrict__ rm, const float* __restrict__ rv,
    unsigned short* __restrict__ Wswz_u, unsigned short* __restrict__ Wswz_f,
    float* __restrict__ d_user)
{
    const int f    = blockIdx.x;          // 0..31
    const int half = f >> 4, nt = (f >> 2) & 3, kt = f & 3;
    const int t    = threadIdx.x;         // 0..63
    const int c    = t & 15, q = t >> 4;

    const int j  = half * 64 + (c >> 2) * 16 + nt * 4 + (c & 3);
    const float a = gamma[j] * rsqrtf(rv[j] + EPS);
    const int k0 = kt * 32 + q * 8;

    unsigned short wu[8], wf[8];
    #pragma unroll
    for (int i = 0; i < 8; ++i) {
        wu[i] = f2bf_rne(a * W1[(size_t)j * (2 * H) + k0 + i]);
        wf[i] = f2bf_rne(a * W1[(size_t)j * (2 * H) + H + k0 + i]);
    }
    const size_t dst = (size_t)f * 512 + (size_t)t * 8;   // ushort units
    #pragma unroll
    for (int i = 0; i < 8; ++i) { Wswz_u[dst + i] = wu[i]; Wswz_f[dst + i] = wf[i]; }

    if (kt == 0 && q == 0) d_user[j] = a * (b1[j] - rm[j]) + beta[j];
}

// ---------------------------------------------------------------------------
// proj_mfma v5 (unchanged from round 7): W register-stationary, col-half
// split across wave pairs, one contiguous 32-row chunk per block, permuted-j
// fragments -> contiguous 2x16B epilogue stores. Z split hi+lo (2 MFMAs).
// ---------------------------------------------------------------------------
__global__ __launch_bounds__(256, 4) void proj_mfma(
    const float* __restrict__ z_user, const float* __restrict__ z_food,
    const unsigned short* __restrict__ Wswz_u, const unsigned short* __restrict__ Wswz_f,
    const float* __restrict__ d_user,
    unsigned short* __restrict__ U, unsigned short* __restrict__ F,
    int n_users, int n_foods, int GU)
{
    const bool userMode = (blockIdx.x < (unsigned)GU);
    const float* Z;
    const unsigned short* Wsrc;
    unsigned short* Out;
    int n, blk0;
    if (userMode) { Z = z_user; Wsrc = Wswz_u; Out = U; n = n_users; blk0 = blockIdx.x; }
    else          { Z = z_food; Wsrc = Wswz_f; Out = F; n = n_foods; blk0 = blockIdx.x - GU; }
    const int tiles = n >> 4;

    const int wave = threadIdx.x >> 6;
    const int lane = threadIdx.x & 63;
    const int c = lane & 15;
    const int q = lane >> 4;
    const int half    = wave & 1;
    const int tilepar = wave >> 1;

    const int t = blk0 * 2 + tilepar;
    if (t >= tiles) return;

    bf16x8 wf[4][4];
    #pragma unroll
    for (int nt = 0; nt < 4; ++nt)
        #pragma unroll
        for (int kt = 0; kt < 4; ++kt)
            wf[nt][kt] = *(const bf16x8*)(Wsrc + (size_t)(half * 16 + nt * 4 + kt) * 512 + lane * 8);

    f32x4 acc[4];
    #pragma unroll
    for (int nt = 0; nt < 4; ++nt) {
        if (userMode) {
            float4 d = *(const float4*)(d_user + half * 64 + q * 16 + nt * 4);
            acc[nt] = (f32x4){d.x, d.y, d.z, d.w};
        } else {
            acc[nt] = (f32x4){0.f, 0.f, 0.f, 0.f};
        }
    }

    const int r = t * 16 + c;
    const float* zrow = Z + (size_t)r * H;

    #pragma unroll
    for (int kt = 0; kt < 4; ++kt) {
        const int k0 = kt * 32 + q * 8;
        float4 za = ((const float4*)(zrow + k0))[0];
        float4 zb = ((const float4*)(zrow + k0))[1];
        bf16x8 zhi, zlo;
        {
            float v[8] = {za.x, za.y, za.z, za.w, zb.x, zb.y, zb.z, zb.w};
            #pragma unroll
            for (int i = 0; i < 8; ++i) {
                unsigned short hi = f2bf_rne(v[i]);
                unsigned short lo = f2bf_rne(v[i] - bf2f(hi));
                zhi[i] = (short)hi; zlo[i] = (short)lo;
            }
        }
        #pragma unroll
        for (int nt = 0; nt < 4; ++nt) {
            acc[nt] = __builtin_amdgcn_mfma_f32_16x16x32_bf16(wf[nt][kt], zhi, acc[nt], 0, 0, 0);
            acc[nt] = __builtin_amdgcn_mfma_f32_16x16x32_bf16(wf[nt][kt], zlo, acc[nt], 0, 0, 0);
        }
    }

    unsigned short* obase = Out + (size_t)r * H + half * 64 + q * 16;
    uint4 p0, p1;
    p0.x = pack2(acc[0][0], acc[0][1]); p0.y = pack2(acc[0][2], acc[0][3]);
    p0.z = pack2(acc[1][0], acc[1][1]); p0.w = pack2(acc[1][2], acc[1][3]);
    p1.x = pack2(acc[2][0], acc[2][1]); p1.y = pack2(acc[2][2], acc[2][3]);
    p1.z = pack2(acc[3][0], acc[3][1]); p1.w = pack2(acc[3][2], acc[3][3]);
    *(uint4*)(obase)     = p0;
    *(uint4*)(obase + 8) = p1;
}

// ---------------------------------------------------------------------------
// edge kernel v2: 4-way unrolled gather for latency hiding.
// Each 16-lane group processes 4 edges per iteration: batch index loads,
// issue all 8 row-gathers back-to-back (16 KB in flight per wave), then
// compute/reduce/store. Accumulation math identical to previous rounds.
// ---------------------------------------------------------------------------
#define EUN 4
__global__ __launch_bounds__(256) void edge_kernel(
    const unsigned short* __restrict__ U, const unsigned short* __restrict__ F,
    const int* __restrict__ row, const int* __restrict__ col,
    const float* __restrict__ W2, const float* __restrict__ b2,
    float* __restrict__ out, int E)
{
    const int lane = threadIdx.x & 15;
    const int g  = (blockIdx.x * blockDim.x + threadIdx.x) >> 4;
    const int nG = (gridDim.x * blockDim.x) >> 4;

    const float4 w2a = ((const float4*)W2)[2 * lane];
    const float4 w2b = ((const float4*)W2)[2 * lane + 1];
    const float bias = b2[0] + INF_BIAS;

    for (int e0 = g; e0 < E; e0 += EUN * nG) {
        int iu[EUN], ifo[EUN];
        #pragma unroll
        for (int i = 0; i < EUN; ++i) {
            int e  = e0 + i * nG;
            int ec = (e < E) ? e : e0;       // clamp (result discarded)
            iu[i]  = row[ec];
            ifo[i] = col[ec];
        }
        uint4 uv[EUN], fv[EUN];
        #pragma unroll
        for (int i = 0; i < EUN; ++i) {
            uv[i] = ((const uint4*)(U + (size_t)iu[i]  * H))[lane];
            fv[i] = ((const uint4*)(F + (size_t)ifo[i] * H))[lane];
        }
        #pragma unroll
        for (int i = 0; i < EUN; ++i) {
            float2 u0 = unpack2(uv[i].x), f0 = unpack2(fv[i].x);
            float2 u1 = unpack2(uv[i].y), f1 = unpack2(fv[i].y);
            float2 u2 = unpack2(uv[i].z), f2 = unpack2(fv[i].z);
            float2 u3 = unpack2(uv[i].w), f3 = unpack2(fv[i].w);

            float s =
                w2a.x * fmaxf(u0.x + f0.x, 0.0f) +
                w2a.y * fmaxf(u0.y + f0.y, 0.0f) +
                w2a.z * fmaxf(u1.x + f1.x, 0.0f) +
                w2a.w * fmaxf(u1.y + f1.y, 0.0f) +
                w2b.x * fmaxf(u2.x + f2.x, 0.0f) +
                w2b.y * fmaxf(u2.y + f2.y, 0.0f) +
                w2b.z * fmaxf(u3.x + f3.x, 0.0f) +
                w2b.w * fmaxf(u3.y + f3.y, 0.0f);

            s += __shfl_xor(s, 8, 16);
            s += __shfl_xor(s, 4, 16);
            s += __shfl_xor(s, 2, 16);
            s += __shfl_xor(s, 1, 16);

            const int e = e0 + i * nG;
            if (lane == 0 && e < E) {
                float x = s + bias;
                out[e] = 1.0f / (1.0f + __expf(-x));
            }
        }
    }
}

extern "C" void kernel_launch(void* const* d_in, const int* in_sizes, int n_in,
                              void* d_out, int out_size, void* d_ws, size_t ws_size,
                              hipStream_t stream) {
    const float* z_user = (const float*)d_in[0];
    const float* z_food = (const float*)d_in[1];
    const int*   row    = (const int*)d_in[2];
    const int*   col    = (const int*)d_in[3];
    const float* W1     = (const float*)d_in[4];
    const float* b1     = (const float*)d_in[5];
    const float* gamma  = (const float*)d_in[6];
    const float* beta   = (const float*)d_in[7];
    const float* rm     = (const float*)d_in[8];
    const float* rv     = (const float*)d_in[9];
    const float* W2     = (const float*)d_in[10];
    const float* b2     = (const float*)d_in[11];
    float* out = (float*)d_out;

    const int n_users = in_sizes[0] / H;
    const int n_foods = in_sizes[1] / H;
    const int E       = in_sizes[2];

    // workspace layout
    unsigned short* U      = (unsigned short*)d_ws;        // n_users*128 bf16
    unsigned short* F      = U + (size_t)n_users * H;      // n_foods*128 bf16
    unsigned short* Wswz_u = F + (size_t)n_foods * H;      // 128*128 bf16, frag order
    unsigned short* Wswz_f = Wswz_u + H * H;               // 128*128 bf16, frag order
    float*          d_usr  = (float*)(Wswz_f + H * H);     // 128 f32

    prep_kernel<<<32, 64, 0, stream>>>(W1, b1, gamma, beta, rm, rv,
                                       Wswz_u, Wswz_f, d_usr);

    const int GU = (n_users + 31) / 32;
    const int GF = ((n_foods + 15) / 16 + 1) / 2;
    proj_mfma<<<GU + GF, 256, 0, stream>>>(z_user, z_food, Wswz_u, Wswz_f, d_usr,
                                           U, F, n_users, n_foods, GU);

    edge_kernel<<<8192, 256, 0, stream>>>(U, F, row, col, W2, b2, out, E);
}